// Round 1
// baseline (695.173 us; speedup 1.0000x reference)
//
#include <hip/hip_runtime.h>

// CRF log-likelihood forward. B=256, L=1024, T=128, fp32.
// One block per batch; 256 threads = (column j = tid&127, i-half = tid>>7).
// E=exp(trans) column halves in VGPRs (64/thread); p broadcast via LDS float4;
// shift m is a lagged single-lane bound (shift-invariant recurrence => exact).

#define TB 256
#define NB 256
#define LL 1024
#define TT 128
#define LOG2E 1.4426950408889634f
#define LN2f  0.6931471805599453f

__launch_bounds__(256, 1)
__global__ void crf_fwd(const float* __restrict__ inputs,   // B,L,T
                        const int*   __restrict__ tags,     // B,L
                        const int*   __restrict__ slens,    // B
                        const float* __restrict__ trans,    // T,T
                        float* __restrict__ out)            // B
{
    const int b    = blockIdx.x;
    const int tid  = threadIdx.x;
    const int j    = tid & (TT - 1);
    const int half = tid >> 7;          // 0: i=0..63, 1: i=64..127
    const int ibase = half << 6;
    const int lane = tid & 63;
    const int wid  = tid >> 6;

    __shared__ __align__(16) float pLDS[TT];
    __shared__ float sLDS[2 * TT];
    __shared__ float wred[4];
    __shared__ float wsc[4];
    __shared__ float mred[2];

    const int slen = slens[b];
    const float* __restrict__ inb  = inputs + (size_t)b * LL * TT;
    const int*   __restrict__ tagb = tags + b * LL;

    // ---------- sequence score (unary + binary), masked by t < slen ----------
    float sc = 0.f;
    for (int t = tid; t < slen; t += TB) {
        int tg = tagb[t];
        float v = inb[(size_t)t * TT + tg];
        if (t >= 1) v += trans[tagb[t - 1] * TT + tg];
        sc += v;
    }
    #pragma unroll
    for (int off = 32; off > 0; off >>= 1)
        sc += __shfl_xor(sc, off, 64);
    if (lane == 0) wsc[wid] = sc;

    // ---------- E column half into registers: e[k] = exp(trans[ibase+k][j]) ----------
    float e[64];
    #pragma unroll
    for (int k = 0; k < 64; ++k)
        e[k] = __builtin_amdgcn_exp2f(trans[(ibase + k) * TT + j] * LOG2E);

    // ---------- init alpha_0 and initial shift ----------
    float alpha = inb[j];
    if (tid == 0) mred[0] = alpha + 13.0f;   // >= max_j alpha0 (N(0,1) spread << 13)
    __syncthreads();

    float score = wsc[0] + wsc[1] + wsc[2] + wsc[3];
    float mlag  = mred[0];

    int tfin = slen - 1;                 // = clip(slen-2,0,L-2)+1
    if (tfin < 1) tfin = 1;

    float in_cur = inb[TT + j];          // in[1][j]
    int t2 = 2 > tfin ? tfin : 2;
    float in_n1 = inb[(size_t)t2 * TT + j];

    float logZ = 0.f;

    for (int t = 1;; ++t) {
        // prefetch 2 steps ahead (clamped; value unused past tfin)
        int tp = t + 2 > tfin ? tfin : t + 2;
        float in_n2 = inb[(size_t)tp * TT + j];

        float p = __builtin_amdgcn_exp2f((alpha - mlag) * LOG2E);
        if (half == 0) pLDS[j] = p;
        if (tid == 0)  mred[t & 1] = alpha + 13.0f;  // lagged shift for t+1 (ping-pong slot)
        __syncthreads();                             // A: pLDS/mred visible

        float mnext = mred[t & 1];

        const float4* __restrict__ p4 = reinterpret_cast<const float4*>(pLDS + ibase);
        float s0 = 0.f, s1 = 0.f, s2 = 0.f, s3 = 0.f;
        #pragma unroll
        for (int k = 0; k < 16; ++k) {
            float4 v = p4[k];                        // LDS broadcast read
            s0 = fmaf(v.x, e[4 * k + 0], s0);
            s1 = fmaf(v.y, e[4 * k + 1], s1);
            s2 = fmaf(v.z, e[4 * k + 2], s2);
            s3 = fmaf(v.w, e[4 * k + 3], s3);
        }
        float spart = (s0 + s1) + (s2 + s3);
        sLDS[half * TT + j] = spart;
        __syncthreads();                             // B: partials visible

        float stot = sLDS[j] + sLDS[TT + j];
        alpha = in_cur + mlag + __builtin_amdgcn_logf(stot) * LN2f;
        mlag = mnext;
        in_cur = in_n1;
        in_n1 = in_n2;

        if (t == tfin) {                             // uniform branch per block
            // exact logsumexp over final alpha (shift exactness independent of mlag)
            float q = __builtin_amdgcn_exp2f((alpha - mlag) * LOG2E);
            #pragma unroll
            for (int off = 32; off > 0; off >>= 1)
                q += __shfl_xor(q, off, 64);
            if (lane == 0) wred[wid] = q;
            __syncthreads();
            float qs = wred[0] + wred[1];            // waves 0,1 cover j=0..127 (2,3 duplicate)
            logZ = mlag + __builtin_amdgcn_logf(qs) * LN2f;
            break;
        }
    }

    if (tid == 0) out[b] = score - logZ;
}

extern "C" void kernel_launch(void* const* d_in, const int* in_sizes, int n_in,
                              void* d_out, int out_size, void* d_ws, size_t ws_size,
                              hipStream_t stream) {
    const float* inputs = (const float*)d_in[0];
    const int*   tags   = (const int*)d_in[1];
    const int*   slens  = (const int*)d_in[2];
    const float* trans  = (const float*)d_in[3];
    float* out = (float*)d_out;
    crf_fwd<<<NB, TB, 0, stream>>>(inputs, tags, slens, trans, out);
}

// Round 2
// 615.662 us; speedup vs baseline: 1.1291x; 1.1291x over previous
//
#include <hip/hip_runtime.h>

// CRF log-likelihood, linear-domain scan + v_readlane broadcast.
// One block/batch (256 blocks, 1/CU), 4 waves:
//   W0: cols 0..63,  i 0..63   (maintains q[0..63])
//   W1: cols 64..127,i 64..127 (maintains q[64..127])
//   W2: cols 0..63,  i 64..127 (maintains dup q[64..127])
//   W3: cols 64..127,i 0..63   (maintains dup q[0..63])
// Each wave self-supplies p=q via v_readlane from its own registers (VALU pipe,
// per-SIMD parallel) -> no LDS broadcast in the inner loop. One barrier/step,
// ping-pong LDS partial/c buffers. q renormed by c=rcp(S0) each step; scale
// tracked in Dacc (log2). exp(in) computed in the prefetch pipeline.

#define TB 256
#define NB 256
#define LL 1024
#define TT 128
#define L2E  1.4426950408889634f
#define LN2f 0.6931471805599453f

__device__ __forceinline__ float rl(float v, int k) {
    return __uint_as_float(__builtin_amdgcn_readlane(__float_as_uint(v), k));
}

__launch_bounds__(256, 1)
__global__ void crf_fwd(const float* __restrict__ inputs,   // B,L,T
                        const int*   __restrict__ tags,     // B,L
                        const int*   __restrict__ slens,    // B
                        const float* __restrict__ trans,    // T,T
                        float* __restrict__ out)            // B
{
    const int b    = blockIdx.x;
    const int tid  = threadIdx.x;
    const int lane = tid & 63;
    const int wid  = __builtin_amdgcn_readfirstlane(tid >> 6);
    const int ihalf = (wid == 1 || wid == 2) ? 1 : 0;
    const int mcol  = ihalf * 64 + lane;                       // maintained col
    const int ccol  = (wid == 1 || wid == 3) ? 64 + lane : lane; // computed col

    __shared__ float pbuf[2][2][TT];   // [t&1][ihalf][col]
    __shared__ float cbuf[2];
    __shared__ float wred[4];
    __shared__ float wsc[4];

    const int slen = slens[b];
    const float* __restrict__ inb  = inputs + (size_t)b * LL * TT;
    const int*   __restrict__ tagb = tags + b * LL;

    // ---------- sequence score (unary + binary), masked ----------
    float sc = 0.f;
    for (int t = tid; t < slen; t += TB) {
        int tg = tagb[t];
        float v = inb[(size_t)t * TT + tg];
        if (t >= 1) v += trans[tagb[t - 1] * TT + tg];
        sc += v;
    }
    #pragma unroll
    for (int off = 32; off > 0; off >>= 1) sc += __shfl_xor(sc, off, 64);
    if (lane == 0) wsc[wid] = sc;
    if (tid == 0) cbuf[1] = 1.0f;      // c for iter 1

    // ---------- E fragment: e[k] = exp(trans[ihalf*64+k][ccol]) ----------
    float e[64];
    #pragma unroll
    for (int k = 0; k < 64; ++k)
        e[k] = __builtin_amdgcn_exp2f(trans[(ihalf * 64 + k) * TT + ccol] * L2E);

    // ---------- init: q0 = exp(in0[mcol] - in0[0]) ----------
    const float in00 = inb[0];
    float q = __builtin_amdgcn_exp2f((inb[mcol] - in00) * L2E);

    int tfin = slen - 1; if (tfin < 1) tfin = 1;

    float raw_cur = inb[TT + mcol];                 // in[1][mcol]
    int t2 = 2 > tfin ? tfin : 2;
    float raw_n1 = inb[(size_t)t2 * TT + mcol];

    float Dacc = 0.f, slogprev = 0.f;
    float logZ = 0.f;

    for (int t = 1;; ++t) {
        int tp = (t + 2 > tfin) ? tfin : t + 2;
        float raw_n2 = inb[(size_t)tp * TT + mcol];         // prefetch
        float einp = __builtin_amdgcn_exp2f(raw_cur * L2E); // off critical path

        // partial s over own i-half for column ccol (readlane broadcast)
        float a0 = 0.f, a1 = 0.f, a2 = 0.f, a3 = 0.f;
        #pragma unroll
        for (int k = 0; k < 64; k += 4) {
            a0 = fmaf(rl(q, k + 0), e[k + 0], a0);
            a1 = fmaf(rl(q, k + 1), e[k + 1], a1);
            a2 = fmaf(rl(q, k + 2), e[k + 2], a2);
            a3 = fmaf(rl(q, k + 3), e[k + 3], a3);
        }
        float part = (a0 + a1) + (a2 + a3);
        pbuf[t & 1][ihalf][ccol] = part;
        Dacc += slogprev;              // Sum_{u<t} log2(S0_u)
        __syncthreads();

        float c = cbuf[t & 1];
        float p0, p1;
        if (wid == 0)      { p0 = part;                p1 = pbuf[t & 1][1][mcol]; }
        else if (wid == 1) { p0 = pbuf[t & 1][0][mcol]; p1 = part; }
        else               { p0 = pbuf[t & 1][0][mcol]; p1 = pbuf[t & 1][1][mcol]; }
        float stot = p0 + p1;          // bit-identical across dup waves
        q = (einp * c) * stot;

        float s0b = rl(stot, 0);       // S0 (valid on W0/W3)

        if (t == tfin) {
            // logZ = in00 + ln2*(Dacc + log2(sum_j q_T[j]))
            float qs = q;
            #pragma unroll
            for (int off = 32; off > 0; off >>= 1) qs += __shfl_xor(qs, off, 64);
            if (lane == 0) wred[wid] = qs;
            __syncthreads();
            float total = wred[0] + wred[1];   // W0 cols + W1 cols
            logZ = in00 + LN2f * (Dacc + __builtin_amdgcn_logf(total));
            break;
        }

        slogprev = __builtin_amdgcn_logf(s0b);          // off critical path
        float cnew = __builtin_amdgcn_rcpf(s0b);
        if (tid == 0) cbuf[(t + 1) & 1] = cnew;
        raw_cur = raw_n1; raw_n1 = raw_n2;
    }

    if (tid == 0) {
        float score = wsc[0] + wsc[1] + wsc[2] + wsc[3];
        out[b] = score - logZ;
    }
}

extern "C" void kernel_launch(void* const* d_in, const int* in_sizes, int n_in,
                              void* d_out, int out_size, void* d_ws, size_t ws_size,
                              hipStream_t stream) {
    const float* inputs = (const float*)d_in[0];
    const int*   tags   = (const int*)d_in[1];
    const int*   slens  = (const int*)d_in[2];
    const float* trans  = (const float*)d_in[3];
    float* out = (float*)d_out;
    crf_fwd<<<NB, TB, 0, stream>>>(inputs, tags, slens, trans, out);
}